// Round 7
// baseline (7063.474 us; speedup 1.0000x reference)
//
#include <hip/hip_runtime.h>
#include <math.h>

typedef __bf16 bf16_t;
typedef __bf16 bf16x8 __attribute__((ext_vector_type(8)));
typedef float f32x4 __attribute__((ext_vector_type(4)));

#define B_ 256
#define H_ 1024

// ---------------------------------------------------------------------------
// GRU fused GEMM+combine, BK=128: C[256,4096] = A[256,K] @ W4[4096,K]^T.
// Tile 64x64, 4 waves, double-buffered LDS, ONE barrier per 128 K (two
// R1-style 64-K halves per interval). Grid (64,4) XCD-remapped.
// W4 row order n' = (c>>4)*64 + g*16 + (c&15); g: 0=r,1=z,2=i_n,3=h_n.
// ---------------------------------------------------------------------------
__global__ __launch_bounds__(256) void gru_gemm128(
    const bf16_t* __restrict__ A, const bf16_t* __restrict__ W,
    const float* __restrict__ bias, int K,
    float* __restrict__ hf,
    bf16_t* __restrict__ d1, int ld1, int off1,
    bf16_t* __restrict__ d2, int ld2, int off2)
{
    __shared__ __align__(16) bf16_t ldsA[2][4][64 * 40];
    __shared__ __align__(16) bf16_t ldsB[2][4][64 * 40];

    int bx = blockIdx.x, by = blockIdx.y;
    {   // XCD-aware remap: XCD x gets n-blocks [x*8, x*8+8)
        int d = by * 64 + bx;
        bx = (d & 7) * 8 + ((d >> 3) & 7);
        by = d >> 6;
    }
    const int bm = by * 64, bn = bx * 64;
    const int tid = threadIdx.x;

    // staging: thread -> (row tid>>2, 16B chunk tid&3); 4 chunk-halves per BK
    const int srow = tid >> 2, schk = tid & 3;
    const bf16_t* gA = A + (size_t)(bm + srow) * K + schk * 8;
    const bf16_t* gW = W + (size_t)(bn + srow) * K + schk * 8;
    const unsigned sa = srow * 40 + schk * 8;

    const int lane = tid & 63, wv = tid >> 6;
    const int quad = lane >> 4, col = lane & 15;
    const unsigned ra = (wv * 16 + col) * 40 + quad * 8;
    const unsigned rb = col * 40 + quad * 8;

    f32x4 acc[4];
#pragma unroll
    for (int j = 0; j < 4; j++)
#pragma unroll
        for (int e = 0; e < 4; e++) acc[j][e] = 0.f;

    int4 pa[4], pb[4];

    // prologue: stage BK0 into buf0, prefetch BK1
#pragma unroll
    for (int h = 0; h < 4; h++) {
        pa[h] = *(const int4*)(gA + h * 32);
        pb[h] = *(const int4*)(gW + h * 32);
    }
    gA += 128; gW += 128;
#pragma unroll
    for (int h = 0; h < 4; h++) {
        *(int4*)&ldsA[0][h][sa] = pa[h];
        *(int4*)&ldsB[0][h][sa] = pb[h];
    }
#pragma unroll
    for (int h = 0; h < 4; h++) {
        pa[h] = *(const int4*)(gA + h * 32);
        pb[h] = *(const int4*)(gW + h * 32);
    }
    gA += 128; gW += 128;

    const int nit = K >> 7;                 // K % 128 == 0 (1280, 2048)
    __syncthreads();

    for (int c = 0; c < nit; ++c) {
        const int cur = c & 1;
        // ---- half 1: chunks 0,1 ----
        bf16x8 af0 = *(const bf16x8*)&ldsA[cur][0][ra];
        bf16x8 af1 = *(const bf16x8*)&ldsA[cur][1][ra];
        bf16x8 b00 = *(const bf16x8*)&ldsB[cur][0][rb];
        bf16x8 b01 = *(const bf16x8*)&ldsB[cur][0][rb + 16 * 40];
        bf16x8 b02 = *(const bf16x8*)&ldsB[cur][0][rb + 32 * 40];
        bf16x8 b03 = *(const bf16x8*)&ldsB[cur][0][rb + 48 * 40];
        bf16x8 b10 = *(const bf16x8*)&ldsB[cur][1][rb];
        bf16x8 b11 = *(const bf16x8*)&ldsB[cur][1][rb + 16 * 40];
        bf16x8 b12 = *(const bf16x8*)&ldsB[cur][1][rb + 32 * 40];
        bf16x8 b13 = *(const bf16x8*)&ldsB[cur][1][rb + 48 * 40];

        // stage next buffer while half-1 reads are in flight
        if (c + 1 < nit) {
            const int nxt = cur ^ 1;
#pragma unroll
            for (int h = 0; h < 4; h++) {
                *(int4*)&ldsA[nxt][h][sa] = pa[h];
                *(int4*)&ldsB[nxt][h][sa] = pb[h];
            }
            if (c + 2 < nit) {
#pragma unroll
                for (int h = 0; h < 4; h++) {
                    pa[h] = *(const int4*)(gA + h * 32);
                    pb[h] = *(const int4*)(gW + h * 32);
                }
                gA += 128; gW += 128;
            }
        }

        acc[0] = __builtin_amdgcn_mfma_f32_16x16x32_bf16(af0, b00, acc[0], 0, 0, 0);
        acc[1] = __builtin_amdgcn_mfma_f32_16x16x32_bf16(af0, b01, acc[1], 0, 0, 0);
        acc[2] = __builtin_amdgcn_mfma_f32_16x16x32_bf16(af0, b02, acc[2], 0, 0, 0);
        acc[3] = __builtin_amdgcn_mfma_f32_16x16x32_bf16(af0, b03, acc[3], 0, 0, 0);
        acc[0] = __builtin_amdgcn_mfma_f32_16x16x32_bf16(af1, b10, acc[0], 0, 0, 0);
        acc[1] = __builtin_amdgcn_mfma_f32_16x16x32_bf16(af1, b11, acc[1], 0, 0, 0);
        acc[2] = __builtin_amdgcn_mfma_f32_16x16x32_bf16(af1, b12, acc[2], 0, 0, 0);
        acc[3] = __builtin_amdgcn_mfma_f32_16x16x32_bf16(af1, b13, acc[3], 0, 0, 0);

        // ---- half 2: chunks 2,3 ----
        bf16x8 af2 = *(const bf16x8*)&ldsA[cur][2][ra];
        bf16x8 af3 = *(const bf16x8*)&ldsA[cur][3][ra];
        bf16x8 b20 = *(const bf16x8*)&ldsB[cur][2][rb];
        bf16x8 b21 = *(const bf16x8*)&ldsB[cur][2][rb + 16 * 40];
        bf16x8 b22 = *(const bf16x8*)&ldsB[cur][2][rb + 32 * 40];
        bf16x8 b23 = *(const bf16x8*)&ldsB[cur][2][rb + 48 * 40];
        bf16x8 b30 = *(const bf16x8*)&ldsB[cur][3][rb];
        bf16x8 b31 = *(const bf16x8*)&ldsB[cur][3][rb + 16 * 40];
        bf16x8 b32 = *(const bf16x8*)&ldsB[cur][3][rb + 32 * 40];
        bf16x8 b33 = *(const bf16x8*)&ldsB[cur][3][rb + 48 * 40];

        acc[0] = __builtin_amdgcn_mfma_f32_16x16x32_bf16(af2, b20, acc[0], 0, 0, 0);
        acc[1] = __builtin_amdgcn_mfma_f32_16x16x32_bf16(af2, b21, acc[1], 0, 0, 0);
        acc[2] = __builtin_amdgcn_mfma_f32_16x16x32_bf16(af2, b22, acc[2], 0, 0, 0);
        acc[3] = __builtin_amdgcn_mfma_f32_16x16x32_bf16(af2, b23, acc[3], 0, 0, 0);
        acc[0] = __builtin_amdgcn_mfma_f32_16x16x32_bf16(af3, b30, acc[0], 0, 0, 0);
        acc[1] = __builtin_amdgcn_mfma_f32_16x16x32_bf16(af3, b31, acc[1], 0, 0, 0);
        acc[2] = __builtin_amdgcn_mfma_f32_16x16x32_bf16(af3, b32, acc[2], 0, 0, 0);
        acc[3] = __builtin_amdgcn_mfma_f32_16x16x32_bf16(af3, b33, acc[3], 0, 0, 0);

        __syncthreads();   // one barrier per BK=128
    }

    // GRU combine epilogue (R1-verified)
    const int cch = (bn >> 2) + col;
    const float br  = bias[bn + col];
    const float bz  = bias[bn + 16 + col];
    const float bin = bias[bn + 32 + col];
    const float bhn = bias[bn + 48 + col];
#pragma unroll
    for (int r = 0; r < 4; r++) {
        const int m = bm + wv * 16 + quad * 4 + r;
        const float gr  = acc[0][r] + br;
        const float gz  = acc[1][r] + bz;
        const float gin = acc[2][r] + bin;
        const float ghn = acc[3][r] + bhn;
        const float rr = 1.f / (1.f + __expf(-gr));
        const float zz = 1.f / (1.f + __expf(-gz));
        const float nn = tanhf(gin + rr * ghn);
        const size_t hidx = (size_t)m * 1024 + cch;
        const float hnew = (1.f - zz) * nn + zz * hf[hidx];
        hf[hidx] = hnew;
        const bf16_t hb = (bf16_t)hnew;
        d1[(size_t)m * ld1 + off1 + cch] = hb;
        d2[(size_t)m * ld2 + off2 + cch] = hb;
    }
}

// ---------------------------------------------------------------------------
// Generic MFMA GEMM (FC head, R1-exact): C = A @ W^T + bias.
// Tile (NW*16) x 64, BK=64, double-buffered LDS, one barrier per BK.
// ---------------------------------------------------------------------------
template<int NW>
__global__ __launch_bounds__(NW * 64) void gemm_mfma(
    const bf16_t* __restrict__ A, const bf16_t* __restrict__ W,
    const float* __restrict__ bias, int K,
    float* __restrict__ C, int ldc)
{
    constexpr int MT = NW * 16;
    constexpr int R = 4 / NW;
    __shared__ __align__(16) bf16_t ldsA[2][2][MT * 40];
    __shared__ __align__(16) bf16_t ldsB[2][2][64 * 40];

    const int bm = blockIdx.y * MT, bn = blockIdx.x * 64;
    const int tid = threadIdx.x;

    const int srow = tid >> 2, schk = tid & 3;
    const bf16_t* gA = A + (size_t)(bm + srow) * K + schk * 8;
    const bf16_t* gW = W + (size_t)(bn + srow) * K + schk * 8;
    const unsigned sa = srow * 40 + schk * 8;

    const int lane = tid & 63, wv = tid >> 6;
    const int quad = lane >> 4, col = lane & 15;
    const unsigned ra_off = (wv * 16 + col) * 40 + quad * 8;
    const unsigned rb_off = col * 40 + quad * 8;

    f32x4 acc[4];
#pragma unroll
    for (int j = 0; j < 4; j++)
#pragma unroll
        for (int e = 0; e < 4; e++) acc[j][e] = 0.f;

    int4 pa0, pa1, pb0[R], pb1[R];

    pa0 = *(const int4*)gA;
    pa1 = *(const int4*)(gA + 32);
#pragma unroll
    for (int r = 0; r < R; r++) {
        pb0[r] = *(const int4*)(gW + (size_t)(r * MT) * K);
        pb1[r] = *(const int4*)(gW + (size_t)(r * MT) * K + 32);
    }
    gA += 64; gW += 64;

    *(int4*)&ldsA[0][0][sa] = pa0;
    *(int4*)&ldsA[0][1][sa] = pa1;
#pragma unroll
    for (int r = 0; r < R; r++) {
        *(int4*)&ldsB[0][0][sa + r * MT * 40] = pb0[r];
        *(int4*)&ldsB[0][1][sa + r * MT * 40] = pb1[r];
    }

    pa0 = *(const int4*)gA;
    pa1 = *(const int4*)(gA + 32);
#pragma unroll
    for (int r = 0; r < R; r++) {
        pb0[r] = *(const int4*)(gW + (size_t)(r * MT) * K);
        pb1[r] = *(const int4*)(gW + (size_t)(r * MT) * K + 32);
    }
    gA += 64; gW += 64;

    const int nit = K >> 6;
    __syncthreads();

    for (int c = 0; c < nit; ++c) {
        const int cur = c & 1;
        bf16x8 af0 = *(const bf16x8*)&ldsA[cur][0][ra_off];
        bf16x8 af1 = *(const bf16x8*)&ldsA[cur][1][ra_off];
        bf16x8 b00 = *(const bf16x8*)&ldsB[cur][0][rb_off];
        bf16x8 b01 = *(const bf16x8*)&ldsB[cur][0][rb_off + 16 * 40];
        bf16x8 b02 = *(const bf16x8*)&ldsB[cur][0][rb_off + 32 * 40];
        bf16x8 b03 = *(const bf16x8*)&ldsB[cur][0][rb_off + 48 * 40];
        bf16x8 b10 = *(const bf16x8*)&ldsB[cur][1][rb_off];
        bf16x8 b11 = *(const bf16x8*)&ldsB[cur][1][rb_off + 16 * 40];
        bf16x8 b12 = *(const bf16x8*)&ldsB[cur][1][rb_off + 32 * 40];
        bf16x8 b13 = *(const bf16x8*)&ldsB[cur][1][rb_off + 48 * 40];

        if (c + 1 < nit) {
            const int nxt = cur ^ 1;
            *(int4*)&ldsA[nxt][0][sa] = pa0;
            *(int4*)&ldsA[nxt][1][sa] = pa1;
#pragma unroll
            for (int r = 0; r < R; r++) {
                *(int4*)&ldsB[nxt][0][sa + r * MT * 40] = pb0[r];
                *(int4*)&ldsB[nxt][1][sa + r * MT * 40] = pb1[r];
            }
            if (c + 2 < nit) {
                pa0 = *(const int4*)gA;
                pa1 = *(const int4*)(gA + 32);
#pragma unroll
                for (int r = 0; r < R; r++) {
                    pb0[r] = *(const int4*)(gW + (size_t)(r * MT) * K);
                    pb1[r] = *(const int4*)(gW + (size_t)(r * MT) * K + 32);
                }
                gA += 64; gW += 64;
            }
        }

        acc[0] = __builtin_amdgcn_mfma_f32_16x16x32_bf16(af0, b00, acc[0], 0, 0, 0);
        acc[1] = __builtin_amdgcn_mfma_f32_16x16x32_bf16(af0, b01, acc[1], 0, 0, 0);
        acc[2] = __builtin_amdgcn_mfma_f32_16x16x32_bf16(af0, b02, acc[2], 0, 0, 0);
        acc[3] = __builtin_amdgcn_mfma_f32_16x16x32_bf16(af0, b03, acc[3], 0, 0, 0);
        acc[0] = __builtin_amdgcn_mfma_f32_16x16x32_bf16(af1, b10, acc[0], 0, 0, 0);
        acc[1] = __builtin_amdgcn_mfma_f32_16x16x32_bf16(af1, b11, acc[1], 0, 0, 0);
        acc[2] = __builtin_amdgcn_mfma_f32_16x16x32_bf16(af1, b12, acc[2], 0, 0, 0);
        acc[3] = __builtin_amdgcn_mfma_f32_16x16x32_bf16(af1, b13, acc[3], 0, 0, 0);

        __syncthreads();
    }

#pragma unroll
    for (int j = 0; j < 4; j++) {
        const int n = bn + j * 16 + col;
        const float bj = bias[n];
#pragma unroll
        for (int r = 0; r < 4; r++) {
            const int m = bm + wv * 16 + quad * 4 + r;
            C[(size_t)m * ldc + n] = acc[j][r] + bj;
        }
    }
}

// ---------------------------------------------------------------------------
// Build fused GRU weight matrix W4[4096, K] (K = Kx + 1024), bf16, row order
// n' = (c>>4)*64 + g*16 + (c&15)  (R1 version). Also builds fused bias b4.
// ---------------------------------------------------------------------------
__global__ __launch_bounds__(256) void build_w4(
    const float* __restrict__ Wih, const float* __restrict__ Whh,
    const float* __restrict__ bih, const float* __restrict__ bhh,
    bf16_t* __restrict__ W4, float* __restrict__ b4, int Kx)
{
    const int K = Kx + 1024;
    const int tpr = K >> 2;
    const int idx = blockIdx.x * 256 + threadIdx.x;   // over 4096*tpr, exact
    const int np = idx / tpr;
    const int k4 = (idx - np * tpr) * 4;
    const int c = ((np >> 6) << 4) + (np & 15);
    const int g = (np >> 4) & 3;
    const int srow = (g == 0 ? c : (g == 1 ? 1024 + c : 2048 + c));
    float4 v = make_float4(0.f, 0.f, 0.f, 0.f);
    if (k4 < Kx) {
        if (g != 3) v = *(const float4*)(Wih + (size_t)srow * Kx + k4);
    } else {
        if (g != 2) v = *(const float4*)(Whh + (size_t)srow * 1024 + (k4 - Kx));
    }
    bf16_t* dst = W4 + (size_t)np * K + k4;
    dst[0] = (bf16_t)v.x; dst[1] = (bf16_t)v.y;
    dst[2] = (bf16_t)v.z; dst[3] = (bf16_t)v.w;
    if (k4 == 0) {
        b4[np] = (g == 0) ? bih[c] + bhh[c]
               : (g == 1) ? bih[1024 + c] + bhh[1024 + c]
               : (g == 2) ? bih[2048 + c] : bhh[2048 + c];
    }
}

// fp32 -> bf16 convert (4 elems/thread, exact grid)
__global__ __launch_bounds__(256) void conv_bf16(
    const float* __restrict__ src, bf16_t* __restrict__ dst)
{
    const int i4 = (blockIdx.x * 256 + threadIdx.x) * 4;
    float4 v = *(const float4*)(src + i4);
    dst[i4 + 0] = (bf16_t)v.x; dst[i4 + 1] = (bf16_t)v.y;
    dst[i4 + 2] = (bf16_t)v.z; dst[i4 + 3] = (bf16_t)v.w;
}

// ---------------------------------------------------------------------------
// init: h0f/h1f fp32 state, A0[0] = [bf16(0) | bf16(h0)], A1[0][:,1024:] = bf16(h1)
// ---------------------------------------------------------------------------
__global__ __launch_bounds__(256) void init_state(
    const float* __restrict__ hidden, float* __restrict__ h0f,
    float* __restrict__ h1f, bf16_t* __restrict__ A0_0, bf16_t* __restrict__ A1_0)
{
    const int i = blockIdx.x * 256 + threadIdx.x;   // over 262144
    const int m = i >> 10, c = i & 1023;
    const float h0 = hidden[i], h1 = hidden[262144 + i];
    h0f[i] = h0; h1f[i] = h1;
    A0_0[(size_t)m * 1280 + 256 + c] = (bf16_t)h0;
    A1_0[(size_t)m * 2048 + 1024 + c] = (bf16_t)h1;
    if (c < 256) A0_0[(size_t)m * 1280 + c] = (bf16_t)0.f;
}

// ---------------------------------------------------------------------------
// LayerNorm + exact GELU, bf16 output. One row per 256-thread block.
// ---------------------------------------------------------------------------
__device__ __forceinline__ float block_reduce_sum(float v, float* red)
{
#pragma unroll
    for (int o = 32; o > 0; o >>= 1) v += __shfl_xor(v, o, 64);
    const int wid = threadIdx.x >> 6;
    if ((threadIdx.x & 63) == 0) red[wid] = v;
    __syncthreads();
    float s = red[0] + red[1] + red[2] + red[3];
    __syncthreads();
    return s;
}

template <int N>
__global__ __launch_bounds__(256) void ln_gelu(
    const float* __restrict__ X, const float* __restrict__ g,
    const float* __restrict__ b, bf16_t* __restrict__ Y)
{
    __shared__ float red[4];
    const int row = blockIdx.x;
    const int tid = threadIdx.x;
    constexpr int PT = N / 256;
    float v[PT];
    float s = 0.f;
#pragma unroll
    for (int i = 0; i < PT; i++) {
        v[i] = X[(size_t)row * N + tid + i * 256];
        s += v[i];
    }
    const float mu = block_reduce_sum(s, red) * (1.f / N);
    float s2 = 0.f;
#pragma unroll
    for (int i = 0; i < PT; i++) { float d = v[i] - mu; s2 += d * d; }
    const float var = block_reduce_sum(s2, red) * (1.f / N);
    const float inv = rsqrtf(var + 1e-5f);
#pragma unroll
    for (int i = 0; i < PT; i++) {
        const int c = tid + i * 256;
        const float t = (v[i] - mu) * inv * g[c] + b[c];
        Y[(size_t)row * N + c] = (bf16_t)(0.5f * t * (1.f + erff(t * 0.70710678118654752f)));
    }
}

// ---------------------------------------------------------------------------
// softmax over logits rows; writes dout[b,t,:] fp32 and feedback bf16 into A0
// ---------------------------------------------------------------------------
__global__ __launch_bounds__(256) void softmax_fb(
    const float* __restrict__ logits, float* __restrict__ dout,
    bf16_t* __restrict__ a0w, int t)
{
    const int wv = threadIdx.x >> 6, lane = threadIdx.x & 63;
    const int row = blockIdx.x * 4 + wv;
    float v[4];
#pragma unroll
    for (int j = 0; j < 4; j++) v[j] = logits[(size_t)row * 256 + lane + 64 * j];
    float mx = fmaxf(fmaxf(v[0], v[1]), fmaxf(v[2], v[3]));
#pragma unroll
    for (int o = 32; o > 0; o >>= 1) mx = fmaxf(mx, __shfl_xor(mx, o, 64));
    float e[4], s = 0.f;
#pragma unroll
    for (int j = 0; j < 4; j++) { e[j] = expf(v[j] - mx); s += e[j]; }
#pragma unroll
    for (int o = 32; o > 0; o >>= 1) s += __shfl_xor(s, o, 64);
    const float inv = 1.f / s;
#pragma unroll
    for (int j = 0; j < 4; j++) {
        const float p = e[j] * inv;
        const int c = lane + 64 * j;
        dout[((size_t)row * 64 + t) * 256 + c] = p;
        a0w[(size_t)row * 1280 + c] = (bf16_t)p;
    }
}

extern "C" void kernel_launch(void* const* d_in, const int* in_sizes, int n_in,
                              void* d_out, int out_size, void* d_ws, size_t ws_size,
                              hipStream_t stream)
{
    const float* hidden = (const float*)d_in[0];
    const float* W_ih0  = (const float*)d_in[1];
    const float* W_hh0  = (const float*)d_in[2];
    const float* b_ih0  = (const float*)d_in[3];
    const float* b_hh0  = (const float*)d_in[4];
    const float* W_ih1  = (const float*)d_in[5];
    const float* W_hh1  = (const float*)d_in[6];
    const float* b_ih1  = (const float*)d_in[7];
    const float* b_hh1  = (const float*)d_in[8];
    const float* fc1_w  = (const float*)d_in[9];
    const float* fc1_b  = (const float*)d_in[10];
    const float* ln1_g  = (const float*)d_in[11];
    const float* ln1_b  = (const float*)d_in[12];
    const float* fc2_w  = (const float*)d_in[13];
    const float* fc2_b  = (const float*)d_in[14];
    const float* ln2_g  = (const float*)d_in[15];
    const float* ln2_b  = (const float*)d_in[16];
    const float* fc3_w  = (const float*)d_in[17];
    const float* fc3_b  = (const float*)d_in[18];
    float* dout = (float*)d_out;

    char* p = (char*)d_ws;
    auto alloc = [&](size_t bytes) { void* r = (void*)p; p += (bytes + 255) & ~(size_t)255; return r; };
    float*  h0f   = (float*)alloc(262144 * 4);
    float*  h1f   = (float*)alloc(262144 * 4);
    bf16_t* A0[2] = { (bf16_t*)alloc(256 * 1280 * 2), (bf16_t*)alloc(256 * 1280 * 2) };
    bf16_t* A1[2] = { (bf16_t*)alloc(256 * 2048 * 2), (bf16_t*)alloc(256 * 2048 * 2) };
    bf16_t* h1b   = (bf16_t*)alloc(262144 * 2);
    float*  a1r   = (float*)alloc(262144 * 4);
    bf16_t* a1b   = (bf16_t*)alloc(262144 * 2);
    float*  a2r   = (float*)alloc(131072 * 4);
    bf16_t* a2b   = (bf16_t*)alloc(131072 * 2);
    float*  logits= (float*)alloc(65536 * 4);
    float*  b4_0  = (float*)alloc(4096 * 4);
    float*  b4_1  = (float*)alloc(4096 * 4);
    bf16_t* W4_0  = (bf16_t*)alloc((size_t)4096 * 1280 * 2);
    bf16_t* W4_1  = (bf16_t*)alloc((size_t)4096 * 2048 * 2);
    bf16_t* fc1wb = (bf16_t*)alloc((size_t)1048576 * 2);
    bf16_t* fc2wb = (bf16_t*)alloc((size_t)524288 * 2);
    bf16_t* fc3wb = (bf16_t*)alloc((size_t)131072 * 2);

    // weight prep (runs every launch; ~40us total, graph-safe)
    build_w4<<<5120, 256, 0, stream>>>(W_ih0, W_hh0, b_ih0, b_hh0, W4_0, b4_0, 256);
    build_w4<<<8192, 256, 0, stream>>>(W_ih1, W_hh1, b_ih1, b_hh1, W4_1, b4_1, 1024);
    conv_bf16<<<1024, 256, 0, stream>>>(fc1_w, fc1wb);
    conv_bf16<<<512, 256, 0, stream>>>(fc2_w, fc2wb);
    conv_bf16<<<128, 256, 0, stream>>>(fc3_w, fc3wb);
    init_state<<<1024, 256, 0, stream>>>(hidden, h0f, h1f, A0[0], A1[0]);

    for (int t = 0; t < 64; t++) {
        bf16_t* A0r = A0[t & 1];
        bf16_t* A0w = A0[(t + 1) & 1];
        bf16_t* A1r = A1[t & 1];
        bf16_t* A1w = A1[(t + 1) & 1];

        // GRU layer 0: reads A0r=[out|h0], updates h0f, writes bf16 h0 into
        // A1r[:, :1024] (gru1 this step) and A0w[:, 256:1280] (next step).
        gru_gemm128<<<dim3(64, 4), 256, 0, stream>>>(
            A0r, W4_0, b4_0, 1280,
            h0f, A1r, 2048, 0, A0w, 1280, 256);
        // GRU layer 1: reads A1r=[h0_new|h1_old], updates h1f, writes bf16 h1
        // into A1w[:, 1024:] (next step) and h1b (fc1 input).
        gru_gemm128<<<dim3(64, 4), 256, 0, stream>>>(
            A1r, W4_1, b4_1, 2048,
            h1f, A1w, 2048, 1024, h1b, 1024, 0);
        // FC head (R1-exact)
        gemm_mfma<2><<<dim3(16, 8), 128, 0, stream>>>(
            h1b, fc1wb, fc1_b, 1024, a1r, 1024);
        ln_gelu<1024><<<256, 256, 0, stream>>>(a1r, ln1_g, ln1_b, a1b);
        gemm_mfma<2><<<dim3(8, 8), 128, 0, stream>>>(
            a1b, fc2wb, fc2_b, 1024, a2r, 512);
        ln_gelu<512><<<256, 256, 0, stream>>>(a2r, ln2_g, ln2_b, a2b);
        gemm_mfma<2><<<dim3(4, 8), 128, 0, stream>>>(
            a2b, fc3wb, fc3_b, 512, logits, 256);
        softmax_fb<<<64, 256, 0, stream>>>(logits, dout, A0w, t);
    }
}

// Round 8
// 5183.313 us; speedup vs baseline: 1.3627x; 1.3627x over previous
//
#include <hip/hip_runtime.h>
#include <math.h>

typedef __bf16 bf16_t;
typedef __bf16 bf16x8 __attribute__((ext_vector_type(8)));
typedef float f32x4 __attribute__((ext_vector_type(4)));

#define B_ 256
#define H_ 1024

#define MFMA_BF16 __builtin_amdgcn_mfma_f32_16x16x32_bf16

// ---------------------------------------------------------------------------
// GRU fused GEMM+combine. C[256,4096] = A[256,K] @ W4[4096,K]^T, K=1280|2048.
// Tile 64x64, 4 waves. B (weights) LDS double-buffered, BK=64, ONE barrier
// per BK (R1 schedule). A-fragments load DIRECTLY from global (L2-resident,
// 16B/lane coalesced), prefetched 2 iters ahead in named even/odd registers
// (no runtime-indexed arrays -> no scratch). Grid (64,4) XCD-remapped.
// W4 row order n' = (c>>4)*64 + g*16 + (c&15); g: 0=r,1=z,2=i_n,3=h_n.
// ---------------------------------------------------------------------------
__global__ __launch_bounds__(256) void gru_gemm(
    const bf16_t* __restrict__ A, const bf16_t* __restrict__ W,
    const float* __restrict__ bias, int K,
    float* __restrict__ hf,
    bf16_t* __restrict__ d1, int ld1, int off1,
    bf16_t* __restrict__ d2, int ld2, int off2)
{
    __shared__ __align__(16) bf16_t ldsB[2][2][64 * 40];

    int bx = blockIdx.x, by = blockIdx.y;
    {   // XCD-aware remap: XCD x gets n-blocks [x*8, x*8+8)
        int d = by * 64 + bx;
        bx = (d & 7) * 8 + ((d >> 3) & 7);
        by = d >> 6;
    }
    const int bm = by * 64, bn = bx * 64;
    const int tid = threadIdx.x;

    // B staging: thread -> (row tid>>2, 16B chunk tid&3), R1-exact
    const int srow = tid >> 2, schk = tid & 3;
    const bf16_t* gW = W + (size_t)(bn + srow) * K + schk * 8;
    const unsigned sa = srow * 40 + schk * 8;

    const int lane = tid & 63, wv = tid >> 6;
    const int quad = lane >> 4, col = lane & 15;
    const unsigned rb = col * 40 + quad * 8;

    // A direct-global fragment pointer: lane (col,quad) of wave wv reads
    // A[bm + wv*16 + col][k + quad*8 .. +8] (16B contiguous, coalesced).
    const bf16_t* gA = A + (size_t)(bm + wv * 16 + col) * K + quad * 8;

    f32x4 acc[4];
#pragma unroll
    for (int j = 0; j < 4; j++)
#pragma unroll
        for (int e = 0; e < 4; e++) acc[j][e] = 0.f;

    // ---- prologue ----
    int4 pb0, pb1;
    pb0 = *(const int4*)gW; pb1 = *(const int4*)(gW + 32); gW += 64;
    *(int4*)&ldsB[0][0][sa] = pb0;
    *(int4*)&ldsB[0][1][sa] = pb1;
    pb0 = *(const int4*)gW; pb1 = *(const int4*)(gW + 32); gW += 64;

    // A fragments for iters 0 (even regs) and 1 (odd regs)
    bf16x8 aE0 = *(const bf16x8*)gA;
    bf16x8 aE1 = *(const bf16x8*)(gA + 32);
    bf16x8 aO0 = *(const bf16x8*)(gA + 64);
    bf16x8 aO1 = *(const bf16x8*)(gA + 96);
    gA += 128;

    const int nit = K >> 6;                 // 20 or 32 (even)
    __syncthreads();                        // buf0 ready

    for (int c = 0; c < nit; c += 2) {
        // ================= even iter c (reads buf0, aE) =================
        {
            bf16x8 b00 = *(const bf16x8*)&ldsB[0][0][rb];
            bf16x8 b01 = *(const bf16x8*)&ldsB[0][0][rb + 16 * 40];
            bf16x8 b02 = *(const bf16x8*)&ldsB[0][0][rb + 32 * 40];
            bf16x8 b03 = *(const bf16x8*)&ldsB[0][0][rb + 48 * 40];
            bf16x8 b10 = *(const bf16x8*)&ldsB[0][1][rb];
            bf16x8 b11 = *(const bf16x8*)&ldsB[0][1][rb + 16 * 40];
            bf16x8 b12 = *(const bf16x8*)&ldsB[0][1][rb + 32 * 40];
            bf16x8 b13 = *(const bf16x8*)&ldsB[0][1][rb + 48 * 40];

            // stage chunk c+1 into buf1 (always valid: nit even, c <= nit-2)
            *(int4*)&ldsB[1][0][sa] = pb0;
            *(int4*)&ldsB[1][1][sa] = pb1;
            if (c + 2 < nit) {
                pb0 = *(const int4*)gW; pb1 = *(const int4*)(gW + 32); gW += 64;
                // prefetch A chunk c+2 into even regs (consumed by MFMAs below
                // via the already-read b-frags? no: aE consumed now) --
                // MFMAs first, then overwrite: use temporaries
            }

            acc[0] = MFMA_BF16(aE0, b00, acc[0], 0, 0, 0);
            acc[1] = MFMA_BF16(aE0, b01, acc[1], 0, 0, 0);
            acc[2] = MFMA_BF16(aE0, b02, acc[2], 0, 0, 0);
            acc[3] = MFMA_BF16(aE0, b03, acc[3], 0, 0, 0);
            acc[0] = MFMA_BF16(aE1, b10, acc[0], 0, 0, 0);
            acc[1] = MFMA_BF16(aE1, b11, acc[1], 0, 0, 0);
            acc[2] = MFMA_BF16(aE1, b12, acc[2], 0, 0, 0);
            acc[3] = MFMA_BF16(aE1, b13, acc[3], 0, 0, 0);

            if (c + 2 < nit) {
                aE0 = *(const bf16x8*)gA;
                aE1 = *(const bf16x8*)(gA + 32);
            }
            __syncthreads();
        }
        // ================= odd iter c+1 (reads buf1, aO) =================
        {
            bf16x8 b00 = *(const bf16x8*)&ldsB[1][0][rb];
            bf16x8 b01 = *(const bf16x8*)&ldsB[1][0][rb + 16 * 40];
            bf16x8 b02 = *(const bf16x8*)&ldsB[1][0][rb + 32 * 40];
            bf16x8 b03 = *(const bf16x8*)&ldsB[1][0][rb + 48 * 40];
            bf16x8 b10 = *(const bf16x8*)&ldsB[1][1][rb];
            bf16x8 b11 = *(const bf16x8*)&ldsB[1][1][rb + 16 * 40];
            bf16x8 b12 = *(const bf16x8*)&ldsB[1][1][rb + 32 * 40];
            bf16x8 b13 = *(const bf16x8*)&ldsB[1][1][rb + 48 * 40];

            if (c + 2 < nit) {
                *(int4*)&ldsB[0][0][sa] = pb0;
                *(int4*)&ldsB[0][1][sa] = pb1;
                if (c + 3 < nit) {
                    pb0 = *(const int4*)gW; pb1 = *(const int4*)(gW + 32); gW += 64;
                }
            }

            acc[0] = MFMA_BF16(aO0, b00, acc[0], 0, 0, 0);
            acc[1] = MFMA_BF16(aO0, b01, acc[1], 0, 0, 0);
            acc[2] = MFMA_BF16(aO0, b02, acc[2], 0, 0, 0);
            acc[3] = MFMA_BF16(aO0, b03, acc[3], 0, 0, 0);
            acc[0] = MFMA_BF16(aO1, b10, acc[0], 0, 0, 0);
            acc[1] = MFMA_BF16(aO1, b11, acc[1], 0, 0, 0);
            acc[2] = MFMA_BF16(aO1, b12, acc[2], 0, 0, 0);
            acc[3] = MFMA_BF16(aO1, b13, acc[3], 0, 0, 0);

            if (c + 3 < nit) {
                aO0 = *(const bf16x8*)(gA + 64);
                aO1 = *(const bf16x8*)(gA + 96);
            }
            gA += 128;
            __syncthreads();
        }
    }

    // GRU combine epilogue (R1-verified)
    const int cch = (bn >> 2) + col;
    const float br  = bias[bn + col];
    const float bz  = bias[bn + 16 + col];
    const float bin = bias[bn + 32 + col];
    const float bhn = bias[bn + 48 + col];
#pragma unroll
    for (int r = 0; r < 4; r++) {
        const int m = bm + wv * 16 + quad * 4 + r;
        const float gr  = acc[0][r] + br;
        const float gz  = acc[1][r] + bz;
        const float gin = acc[2][r] + bin;
        const float ghn = acc[3][r] + bhn;
        const float rr = 1.f / (1.f + __expf(-gr));
        const float zz = 1.f / (1.f + __expf(-gz));
        const float nn = tanhf(gin + rr * ghn);
        const size_t hidx = (size_t)m * 1024 + cch;
        const float hnew = (1.f - zz) * nn + zz * hf[hidx];
        hf[hidx] = hnew;
        const bf16_t hb = (bf16_t)hnew;
        d1[(size_t)m * ld1 + off1 + cch] = hb;
        d2[(size_t)m * ld2 + off2 + cch] = hb;
    }
}

// ---------------------------------------------------------------------------
// Generic MFMA GEMM (FC head, R1-exact): C = A @ W^T + bias.
// Tile (NW*16) x 64, BK=64, double-buffered LDS, one barrier per BK.
// ---------------------------------------------------------------------------
template<int NW>
__global__ __launch_bounds__(NW * 64) void gemm_mfma(
    const bf16_t* __restrict__ A, const bf16_t* __restrict__ W,
    const float* __restrict__ bias, int K,
    float* __restrict__ C, int ldc)
{
    constexpr int MT = NW * 16;
    constexpr int R = 4 / NW;
    __shared__ __align__(16) bf16_t ldsA[2][2][MT * 40];
    __shared__ __align__(16) bf16_t ldsB[2][2][64 * 40];

    const int bm = blockIdx.y * MT, bn = blockIdx.x * 64;
    const int tid = threadIdx.x;

    const int srow = tid >> 2, schk = tid & 3;
    const bf16_t* gA = A + (size_t)(bm + srow) * K + schk * 8;
    const bf16_t* gW = W + (size_t)(bn + srow) * K + schk * 8;
    const unsigned sa = srow * 40 + schk * 8;

    const int lane = tid & 63, wv = tid >> 6;
    const int quad = lane >> 4, col = lane & 15;
    const unsigned ra_off = (wv * 16 + col) * 40 + quad * 8;
    const unsigned rb_off = col * 40 + quad * 8;

    f32x4 acc[4];
#pragma unroll
    for (int j = 0; j < 4; j++)
#pragma unroll
        for (int e = 0; e < 4; e++) acc[j][e] = 0.f;

    int4 pa0, pa1, pb0[R], pb1[R];

    pa0 = *(const int4*)gA;
    pa1 = *(const int4*)(gA + 32);
#pragma unroll
    for (int r = 0; r < R; r++) {
        pb0[r] = *(const int4*)(gW + (size_t)(r * MT) * K);
        pb1[r] = *(const int4*)(gW + (size_t)(r * MT) * K + 32);
    }
    gA += 64; gW += 64;

    *(int4*)&ldsA[0][0][sa] = pa0;
    *(int4*)&ldsA[0][1][sa] = pa1;
#pragma unroll
    for (int r = 0; r < R; r++) {
        *(int4*)&ldsB[0][0][sa + r * MT * 40] = pb0[r];
        *(int4*)&ldsB[0][1][sa + r * MT * 40] = pb1[r];
    }

    pa0 = *(const int4*)gA;
    pa1 = *(const int4*)(gA + 32);
#pragma unroll
    for (int r = 0; r < R; r++) {
        pb0[r] = *(const int4*)(gW + (size_t)(r * MT) * K);
        pb1[r] = *(const int4*)(gW + (size_t)(r * MT) * K + 32);
    }
    gA += 64; gW += 64;

    const int nit = K >> 6;
    __syncthreads();

    for (int c = 0; c < nit; ++c) {
        const int cur = c & 1;
        bf16x8 af0 = *(const bf16x8*)&ldsA[cur][0][ra_off];
        bf16x8 af1 = *(const bf16x8*)&ldsA[cur][1][ra_off];
        bf16x8 b00 = *(const bf16x8*)&ldsB[cur][0][rb_off];
        bf16x8 b01 = *(const bf16x8*)&ldsB[cur][0][rb_off + 16 * 40];
        bf16x8 b02 = *(const bf16x8*)&ldsB[cur][0][rb_off + 32 * 40];
        bf16x8 b03 = *(const bf16x8*)&ldsB[cur][0][rb_off + 48 * 40];
        bf16x8 b10 = *(const bf16x8*)&ldsB[cur][1][rb_off];
        bf16x8 b11 = *(const bf16x8*)&ldsB[cur][1][rb_off + 16 * 40];
        bf16x8 b12 = *(const bf16x8*)&ldsB[cur][1][rb_off + 32 * 40];
        bf16x8 b13 = *(const bf16x8*)&ldsB[cur][1][rb_off + 48 * 40];

        if (c + 1 < nit) {
            const int nxt = cur ^ 1;
            *(int4*)&ldsA[nxt][0][sa] = pa0;
            *(int4*)&ldsA[nxt][1][sa] = pa1;
#pragma unroll
            for (int r = 0; r < R; r++) {
                *(int4*)&ldsB[nxt][0][sa + r * MT * 40] = pb0[r];
                *(int4*)&ldsB[nxt][1][sa + r * MT * 40] = pb1[r];
            }
            if (c + 2 < nit) {
                pa0 = *(const int4*)gA;
                pa1 = *(const int4*)(gA + 32);
#pragma unroll
                for (int r = 0; r < R; r++) {
                    pb0[r] = *(const int4*)(gW + (size_t)(r * MT) * K);
                    pb1[r] = *(const int4*)(gW + (size_t)(r * MT) * K + 32);
                }
                gA += 64; gW += 64;
            }
        }

        acc[0] = MFMA_BF16(af0, b00, acc[0], 0, 0, 0);
        acc[1] = MFMA_BF16(af0, b01, acc[1], 0, 0, 0);
        acc[2] = MFMA_BF16(af0, b02, acc[2], 0, 0, 0);
        acc[3] = MFMA_BF16(af0, b03, acc[3], 0, 0, 0);
        acc[0] = MFMA_BF16(af1, b10, acc[0], 0, 0, 0);
        acc[1] = MFMA_BF16(af1, b11, acc[1], 0, 0, 0);
        acc[2] = MFMA_BF16(af1, b12, acc[2], 0, 0, 0);
        acc[3] = MFMA_BF16(af1, b13, acc[3], 0, 0, 0);

        __syncthreads();
    }

#pragma unroll
    for (int j = 0; j < 4; j++) {
        const int n = bn + j * 16 + col;
        const float bj = bias[n];
#pragma unroll
        for (int r = 0; r < 4; r++) {
            const int m = bm + wv * 16 + quad * 4 + r;
            C[(size_t)m * ldc + n] = acc[j][r] + bj;
        }
    }
}

// ---------------------------------------------------------------------------
// Build fused GRU weight matrix W4[4096, K] (K = Kx + 1024), bf16, row order
// n' = (c>>4)*64 + g*16 + (c&15)  (R1 version). Also builds fused bias b4.
// ---------------------------------------------------------------------------
__global__ __launch_bounds__(256) void build_w4(
    const float* __restrict__ Wih, const float* __restrict__ Whh,
    const float* __restrict__ bih, const float* __restrict__ bhh,
    bf16_t* __restrict__ W4, float* __restrict__ b4, int Kx)
{
    const int K = Kx + 1024;
    const int tpr = K >> 2;
    const int idx = blockIdx.x * 256 + threadIdx.x;   // over 4096*tpr, exact
    const int np = idx / tpr;
    const int k4 = (idx - np * tpr) * 4;
    const int c = ((np >> 6) << 4) + (np & 15);
    const int g = (np >> 4) & 3;
    const int srow = (g == 0 ? c : (g == 1 ? 1024 + c : 2048 + c));
    float4 v = make_float4(0.f, 0.f, 0.f, 0.f);
    if (k4 < Kx) {
        if (g != 3) v = *(const float4*)(Wih + (size_t)srow * Kx + k4);
    } else {
        if (g != 2) v = *(const float4*)(Whh + (size_t)srow * 1024 + (k4 - Kx));
    }
    bf16_t* dst = W4 + (size_t)np * K + k4;
    dst[0] = (bf16_t)v.x; dst[1] = (bf16_t)v.y;
    dst[2] = (bf16_t)v.z; dst[3] = (bf16_t)v.w;
    if (k4 == 0) {
        b4[np] = (g == 0) ? bih[c] + bhh[c]
               : (g == 1) ? bih[1024 + c] + bhh[1024 + c]
               : (g == 2) ? bih[2048 + c] : bhh[2048 + c];
    }
}

// fp32 -> bf16 convert (4 elems/thread, exact grid)
__global__ __launch_bounds__(256) void conv_bf16(
    const float* __restrict__ src, bf16_t* __restrict__ dst)
{
    const int i4 = (blockIdx.x * 256 + threadIdx.x) * 4;
    float4 v = *(const float4*)(src + i4);
    dst[i4 + 0] = (bf16_t)v.x; dst[i4 + 1] = (bf16_t)v.y;
    dst[i4 + 2] = (bf16_t)v.z; dst[i4 + 3] = (bf16_t)v.w;
}

// ---------------------------------------------------------------------------
// init: h0f/h1f fp32 state, A0[0] = [bf16(0) | bf16(h0)], A1[0][:,1024:] = bf16(h1)
// ---------------------------------------------------------------------------
__global__ __launch_bounds__(256) void init_state(
    const float* __restrict__ hidden, float* __restrict__ h0f,
    float* __restrict__ h1f, bf16_t* __restrict__ A0_0, bf16_t* __restrict__ A1_0)
{
    const int i = blockIdx.x * 256 + threadIdx.x;   // over 262144
    const int m = i >> 10, c = i & 1023;
    const float h0 = hidden[i], h1 = hidden[262144 + i];
    h0f[i] = h0; h1f[i] = h1;
    A0_0[(size_t)m * 1280 + 256 + c] = (bf16_t)h0;
    A1_0[(size_t)m * 2048 + 1024 + c] = (bf16_t)h1;
    if (c < 256) A0_0[(size_t)m * 1280 + c] = (bf16_t)0.f;
}

// ---------------------------------------------------------------------------
// LayerNorm + exact GELU, bf16 output. One row per 256-thread block.
// ---------------------------------------------------------------------------
__device__ __forceinline__ float block_reduce_sum(float v, float* red)
{
#pragma unroll
    for (int o = 32; o > 0; o >>= 1) v += __shfl_xor(v, o, 64);
    const int wid = threadIdx.x >> 6;
    if ((threadIdx.x & 63) == 0) red[wid] = v;
    __syncthreads();
    float s = red[0] + red[1] + red[2] + red[3];
    __syncthreads();
    return s;
}

template <int N>
__global__ __launch_bounds__(256) void ln_gelu(
    const float* __restrict__ X, const float* __restrict__ g,
    const float* __restrict__ b, bf16_t* __restrict__ Y)
{
    __shared__ float red[4];
    const int row = blockIdx.x;
    const int tid = threadIdx.x;
    constexpr int PT = N / 256;
    float v[PT];
    float s = 0.f;
#pragma unroll
    for (int i = 0; i < PT; i++) {
        v[i] = X[(size_t)row * N + tid + i * 256];
        s += v[i];
    }
    const float mu = block_reduce_sum(s, red) * (1.f / N);
    float s2 = 0.f;
#pragma unroll
    for (int i = 0; i < PT; i++) { float d = v[i] - mu; s2 += d * d; }
    const float var = block_reduce_sum(s2, red) * (1.f / N);
    const float inv = rsqrtf(var + 1e-5f);
#pragma unroll
    for (int i = 0; i < PT; i++) {
        const int c = tid + i * 256;
        const float t = (v[i] - mu) * inv * g[c] + b[c];
        Y[(size_t)row * N + c] = (bf16_t)(0.5f * t * (1.f + erff(t * 0.70710678118654752f)));
    }
}

// ---------------------------------------------------------------------------
// softmax over logits rows; writes dout[b,t,:] fp32 and feedback bf16 into A0
// ---------------------------------------------------------------------------
__global__ __launch_bounds__(256) void softmax_fb(
    const float* __restrict__ logits, float* __restrict__ dout,
    bf16_t* __restrict__ a0w, int t)
{
    const int wv = threadIdx.x >> 6, lane = threadIdx.x & 63;
    const int row = blockIdx.x * 4 + wv;
    float v[4];
#pragma unroll
    for (int j = 0; j < 4; j++) v[j] = logits[(size_t)row * 256 + lane + 64 * j];
    float mx = fmaxf(fmaxf(v[0], v[1]), fmaxf(v[2], v[3]));
#pragma unroll
    for (int o = 32; o > 0; o >>= 1) mx = fmaxf(mx, __shfl_xor(mx, o, 64));
    float e[4], s = 0.f;
#pragma unroll
    for (int j = 0; j < 4; j++) { e[j] = expf(v[j] - mx); s += e[j]; }
#pragma unroll
    for (int o = 32; o > 0; o >>= 1) s += __shfl_xor(s, o, 64);
    const float inv = 1.f / s;
#pragma unroll
    for (int j = 0; j < 4; j++) {
        const float p = e[j] * inv;
        const int c = lane + 64 * j;
        dout[((size_t)row * 64 + t) * 256 + c] = p;
        a0w[(size_t)row * 1280 + c] = (bf16_t)p;
    }
}

extern "C" void kernel_launch(void* const* d_in, const int* in_sizes, int n_in,
                              void* d_out, int out_size, void* d_ws, size_t ws_size,
                              hipStream_t stream)
{
    const float* hidden = (const float*)d_in[0];
    const float* W_ih0  = (const float*)d_in[1];
    const float* W_hh0  = (const float*)d_in[2];
    const float* b_ih0  = (const float*)d_in[3];
    const float* b_hh0  = (const float*)d_in[4];
    const float* W_ih1  = (const float*)d_in[5];
    const float* W_hh1  = (const float*)d_in[6];
    const float* b_ih1  = (const float*)d_in[7];
    const float* b_hh1  = (const float*)d_in[8];
    const float* fc1_w  = (const float*)d_in[9];
    const float* fc1_b  = (const float*)d_in[10];
    const float* ln1_g  = (const float*)d_in[11];
    const float* ln1_b  = (const float*)d_in[12];
    const float* fc2_w  = (const float*)d_in[13];
    const float* fc2_b  = (const float*)d_in[14];
    const float* ln2_g  = (const float*)d_in[15];
    const float* ln2_b  = (const float*)d_in[16];
    const float* fc3_w  = (const float*)d_in[17];
    const float* fc3_b  = (const float*)d_in[18];
    float* dout = (float*)d_out;

    char* p = (char*)d_ws;
    auto alloc = [&](size_t bytes) { void* r = (void*)p; p += (bytes + 255) & ~(size_t)255; return r; };
    float*  h0f   = (float*)alloc(262144 * 4);
    float*  h1f   = (float*)alloc(262144 * 4);
    bf16_t* A0[2] = { (bf16_t*)alloc(256 * 1280 * 2), (bf16_t*)alloc(256 * 1280 * 2) };
    bf16_t* A1[2] = { (bf16_t*)alloc(256 * 2048 * 2), (bf16_t*)alloc(256 * 2048 * 2) };
    bf16_t* h1b   = (bf16_t*)alloc(262144 * 2);
    float*  a1r   = (float*)alloc(262144 * 4);
    bf16_t* a1b   = (bf16_t*)alloc(262144 * 2);
    float*  a2r   = (float*)alloc(131072 * 4);
    bf16_t* a2b   = (bf16_t*)alloc(131072 * 2);
    float*  logits= (float*)alloc(65536 * 4);
    float*  b4_0  = (float*)alloc(4096 * 4);
    float*  b4_1  = (float*)alloc(4096 * 4);
    bf16_t* W4_0  = (bf16_t*)alloc((size_t)4096 * 1280 * 2);
    bf16_t* W4_1  = (bf16_t*)alloc((size_t)4096 * 2048 * 2);
    bf16_t* fc1wb = (bf16_t*)alloc((size_t)1048576 * 2);
    bf16_t* fc2wb = (bf16_t*)alloc((size_t)524288 * 2);
    bf16_t* fc3wb = (bf16_t*)alloc((size_t)131072 * 2);

    // weight prep (runs every launch; ~40us total, graph-safe)
    build_w4<<<5120, 256, 0, stream>>>(W_ih0, W_hh0, b_ih0, b_hh0, W4_0, b4_0, 256);
    build_w4<<<8192, 256, 0, stream>>>(W_ih1, W_hh1, b_ih1, b_hh1, W4_1, b4_1, 1024);
    conv_bf16<<<1024, 256, 0, stream>>>(fc1_w, fc1wb);
    conv_bf16<<<512, 256, 0, stream>>>(fc2_w, fc2wb);
    conv_bf16<<<128, 256, 0, stream>>>(fc3_w, fc3wb);
    init_state<<<1024, 256, 0, stream>>>(hidden, h0f, h1f, A0[0], A1[0]);

    for (int t = 0; t < 64; t++) {
        bf16_t* A0r = A0[t & 1];
        bf16_t* A0w = A0[(t + 1) & 1];
        bf16_t* A1r = A1[t & 1];
        bf16_t* A1w = A1[(t + 1) & 1];

        // GRU layer 0: reads A0r=[out|h0], updates h0f, writes bf16 h0 into
        // A1r[:, :1024] (gru1 this step) and A0w[:, 256:1280] (next step).
        gru_gemm<<<dim3(64, 4), 256, 0, stream>>>(
            A0r, W4_0, b4_0, 1280,
            h0f, A1r, 2048, 0, A0w, 1280, 256);
        // GRU layer 1: reads A1r=[h0_new|h1_old], updates h1f, writes bf16 h1
        // into A1w[:, 1024:] (next step) and h1b (fc1 input).
        gru_gemm<<<dim3(64, 4), 256, 0, stream>>>(
            A1r, W4_1, b4_1, 2048,
            h1f, A1w, 2048, 1024, h1b, 1024, 0);
        // FC head (R1-exact)
        gemm_mfma<2><<<dim3(16, 8), 128, 0, stream>>>(
            h1b, fc1wb, fc1_b, 1024, a1r, 1024);
        ln_gelu<1024><<<256, 256, 0, stream>>>(a1r, ln1_g, ln1_b, a1b);
        gemm_mfma<2><<<dim3(8, 8), 128, 0, stream>>>(
            a1b, fc2wb, fc2_b, 1024, a2r, 512);
        ln_gelu<512><<<256, 256, 0, stream>>>(a2r, ln2_g, ln2_b, a2b);
        gemm_mfma<2><<<dim3(4, 8), 128, 0, stream>>>(
            a2b, fc3wb, fc3_b, 512, logits, 256);
        softmax_fb<<<64, 256, 0, stream>>>(logits, dout, A0w, t);
    }
}

// Round 9
// 4648.903 us; speedup vs baseline: 1.5194x; 1.1150x over previous
//
#include <hip/hip_runtime.h>
#include <math.h>

typedef __bf16 bf16_t;
typedef __bf16 bf16x8 __attribute__((ext_vector_type(8)));
typedef float f32x4 __attribute__((ext_vector_type(4)));

#define B_ 256
#define H_ 1024

// ---------------------------------------------------------------------------
// MFMA GEMM: C[M,N] = A[M,K](bf16) @ W[N,K](bf16)^T (+bias)
// Tile: (NW*16) x 64, BK=64 (two 32-chunks per stage), double-buffered LDS,
// ONE barrier per BK. NW waves, wave w computes rows [w*16,w*16+16) x 64 cols.
// EPI 0: C fp32 = acc + bias.
// EPI 1: GRU combine epilogue (weights pre-reordered by build_w4).
// (R1-verified: best measured configuration, 4655 us end-to-end.)
// ---------------------------------------------------------------------------
template<int NW, int EPI>
__global__ __launch_bounds__(NW * 64) void gemm_mfma(
    const bf16_t* __restrict__ A, const bf16_t* __restrict__ W,
    const float* __restrict__ bias, int K,
    float* __restrict__ C, int ldc,
    float* __restrict__ hf,
    bf16_t* __restrict__ d1, int ld1, int off1,
    bf16_t* __restrict__ d2, int ld2, int off2)
{
    constexpr int MT = NW * 16;
    constexpr int R = 4 / NW;              // B-row loads per thread per chunk
    __shared__ __align__(16) bf16_t ldsA[2][2][MT * 40];
    __shared__ __align__(16) bf16_t ldsB[2][2][64 * 40];

    int bx = blockIdx.x, by = blockIdx.y;
    if (EPI == 1) {
        int d = by * 64 + bx;
        bx = (d & 7) * 8 + ((d >> 3) & 7);
        by = d >> 6;
    }
    const int bm = by * MT, bn = bx * 64;
    const int tid = threadIdx.x;

    const int srow = tid >> 2, schk = tid & 3;
    const bf16_t* gA = A + (size_t)(bm + srow) * K + schk * 8;
    const bf16_t* gW = W + (size_t)(bn + srow) * K + schk * 8;
    const unsigned sa = srow * 40 + schk * 8;

    const int lane = tid & 63, wv = tid >> 6;
    const int quad = lane >> 4, col = lane & 15;
    const unsigned ra_off = (wv * 16 + col) * 40 + quad * 8;
    const unsigned rb_off = col * 40 + quad * 8;

    f32x4 acc[4];
#pragma unroll
    for (int j = 0; j < 4; j++)
#pragma unroll
        for (int e = 0; e < 4; e++) acc[j][e] = 0.f;

    int4 pa0, pa1, pb0[R], pb1[R];

    pa0 = *(const int4*)gA;
    pa1 = *(const int4*)(gA + 32);
#pragma unroll
    for (int r = 0; r < R; r++) {
        pb0[r] = *(const int4*)(gW + (size_t)(r * MT) * K);
        pb1[r] = *(const int4*)(gW + (size_t)(r * MT) * K + 32);
    }
    gA += 64; gW += 64;

    *(int4*)&ldsA[0][0][sa] = pa0;
    *(int4*)&ldsA[0][1][sa] = pa1;
#pragma unroll
    for (int r = 0; r < R; r++) {
        *(int4*)&ldsB[0][0][sa + r * MT * 40] = pb0[r];
        *(int4*)&ldsB[0][1][sa + r * MT * 40] = pb1[r];
    }

    pa0 = *(const int4*)gA;
    pa1 = *(const int4*)(gA + 32);
#pragma unroll
    for (int r = 0; r < R; r++) {
        pb0[r] = *(const int4*)(gW + (size_t)(r * MT) * K);
        pb1[r] = *(const int4*)(gW + (size_t)(r * MT) * K + 32);
    }
    gA += 64; gW += 64;

    const int nit = K >> 6;
    __syncthreads();

    for (int c = 0; c < nit; ++c) {
        const int cur = c & 1;
        bf16x8 af0 = *(const bf16x8*)&ldsA[cur][0][ra_off];
        bf16x8 af1 = *(const bf16x8*)&ldsA[cur][1][ra_off];
        bf16x8 b00 = *(const bf16x8*)&ldsB[cur][0][rb_off];
        bf16x8 b01 = *(const bf16x8*)&ldsB[cur][0][rb_off + 16 * 40];
        bf16x8 b02 = *(const bf16x8*)&ldsB[cur][0][rb_off + 32 * 40];
        bf16x8 b03 = *(const bf16x8*)&ldsB[cur][0][rb_off + 48 * 40];
        bf16x8 b10 = *(const bf16x8*)&ldsB[cur][1][rb_off];
        bf16x8 b11 = *(const bf16x8*)&ldsB[cur][1][rb_off + 16 * 40];
        bf16x8 b12 = *(const bf16x8*)&ldsB[cur][1][rb_off + 32 * 40];
        bf16x8 b13 = *(const bf16x8*)&ldsB[cur][1][rb_off + 48 * 40];

        if (c + 1 < nit) {
            const int nxt = cur ^ 1;
            *(int4*)&ldsA[nxt][0][sa] = pa0;
            *(int4*)&ldsA[nxt][1][sa] = pa1;
#pragma unroll
            for (int r = 0; r < R; r++) {
                *(int4*)&ldsB[nxt][0][sa + r * MT * 40] = pb0[r];
                *(int4*)&ldsB[nxt][1][sa + r * MT * 40] = pb1[r];
            }
            if (c + 2 < nit) {
                pa0 = *(const int4*)gA;
                pa1 = *(const int4*)(gA + 32);
#pragma unroll
                for (int r = 0; r < R; r++) {
                    pb0[r] = *(const int4*)(gW + (size_t)(r * MT) * K);
                    pb1[r] = *(const int4*)(gW + (size_t)(r * MT) * K + 32);
                }
                gA += 64; gW += 64;
            }
        }

        acc[0] = __builtin_amdgcn_mfma_f32_16x16x32_bf16(af0, b00, acc[0], 0, 0, 0);
        acc[1] = __builtin_amdgcn_mfma_f32_16x16x32_bf16(af0, b01, acc[1], 0, 0, 0);
        acc[2] = __builtin_amdgcn_mfma_f32_16x16x32_bf16(af0, b02, acc[2], 0, 0, 0);
        acc[3] = __builtin_amdgcn_mfma_f32_16x16x32_bf16(af0, b03, acc[3], 0, 0, 0);
        acc[0] = __builtin_amdgcn_mfma_f32_16x16x32_bf16(af1, b10, acc[0], 0, 0, 0);
        acc[1] = __builtin_amdgcn_mfma_f32_16x16x32_bf16(af1, b11, acc[1], 0, 0, 0);
        acc[2] = __builtin_amdgcn_mfma_f32_16x16x32_bf16(af1, b12, acc[2], 0, 0, 0);
        acc[3] = __builtin_amdgcn_mfma_f32_16x16x32_bf16(af1, b13, acc[3], 0, 0, 0);

        __syncthreads();
    }

    if (EPI == 0) {
#pragma unroll
        for (int j = 0; j < 4; j++) {
            const int n = bn + j * 16 + col;
            const float bj = bias[n];
#pragma unroll
            for (int r = 0; r < 4; r++) {
                const int m = bm + wv * 16 + quad * 4 + r;
                C[(size_t)m * ldc + n] = acc[j][r] + bj;
            }
        }
    } else {
        const int cch = (bn >> 2) + col;
        const float br  = bias[bn + col];
        const float bz  = bias[bn + 16 + col];
        const float bin = bias[bn + 32 + col];
        const float bhn = bias[bn + 48 + col];
#pragma unroll
        for (int r = 0; r < 4; r++) {
            const int m = bm + wv * 16 + quad * 4 + r;
            const float gr  = acc[0][r] + br;
            const float gz  = acc[1][r] + bz;
            const float gin = acc[2][r] + bin;
            const float ghn = acc[3][r] + bhn;
            const float rr = 1.f / (1.f + __expf(-gr));
            const float zz = 1.f / (1.f + __expf(-gz));
            const float nn = tanhf(gin + rr * ghn);
            const size_t hidx = (size_t)m * 1024 + cch;
            const float hnew = (1.f - zz) * nn + zz * hf[hidx];
            hf[hidx] = hnew;
            const bf16_t hb = (bf16_t)hnew;
            d1[(size_t)m * ld1 + off1 + cch] = hb;
            d2[(size_t)m * ld2 + off2 + cch] = hb;
        }
    }
}

// ---------------------------------------------------------------------------
// Build fused GRU weight matrix W4[4096, K] (K = Kx + 1024), bf16, with row
// order n' = (c>>4)*64 + g*16 + (c&15); g: 0=r, 1=z, 2=i_n (x only), 3=h_n
// (h only). Also builds fused bias b4.
// ---------------------------------------------------------------------------
__global__ __launch_bounds__(256) void build_w4(
    const float* __restrict__ Wih, const float* __restrict__ Whh,
    const float* __restrict__ bih, const float* __restrict__ bhh,
    bf16_t* __restrict__ W4, float* __restrict__ b4, int Kx)
{
    const int K = Kx + 1024;
    const int tpr = K >> 2;
    const int idx = blockIdx.x * 256 + threadIdx.x;   // over 4096*tpr, exact
    const int np = idx / tpr;
    const int k4 = (idx - np * tpr) * 4;
    const int c = ((np >> 6) << 4) + (np & 15);
    const int g = (np >> 4) & 3;
    const int srow = (g == 0 ? c : (g == 1 ? 1024 + c : 2048 + c));
    float4 v = make_float4(0.f, 0.f, 0.f, 0.f);
    if (k4 < Kx) {
        if (g != 3) v = *(const float4*)(Wih + (size_t)srow * Kx + k4);
    } else {
        if (g != 2) v = *(const float4*)(Whh + (size_t)srow * 1024 + (k4 - Kx));
    }
    bf16_t* dst = W4 + (size_t)np * K + k4;
    dst[0] = (bf16_t)v.x; dst[1] = (bf16_t)v.y;
    dst[2] = (bf16_t)v.z; dst[3] = (bf16_t)v.w;
    if (k4 == 0) {
        b4[np] = (g == 0) ? bih[c] + bhh[c]
               : (g == 1) ? bih[1024 + c] + bhh[1024 + c]
               : (g == 2) ? bih[2048 + c] : bhh[2048 + c];
    }
}

// fp32 -> bf16 convert (4 elems/thread, exact grid)
__global__ __launch_bounds__(256) void conv_bf16(
    const float* __restrict__ src, bf16_t* __restrict__ dst)
{
    const int i4 = (blockIdx.x * 256 + threadIdx.x) * 4;
    float4 v = *(const float4*)(src + i4);
    dst[i4 + 0] = (bf16_t)v.x; dst[i4 + 1] = (bf16_t)v.y;
    dst[i4 + 2] = (bf16_t)v.z; dst[i4 + 3] = (bf16_t)v.w;
}

// ---------------------------------------------------------------------------
// init: h0f/h1f fp32 state, A0[0] = [bf16(0) | bf16(h0)], A1[0][:,1024:] = bf16(h1)
// ---------------------------------------------------------------------------
__global__ __launch_bounds__(256) void init_state(
    const float* __restrict__ hidden, float* __restrict__ h0f,
    float* __restrict__ h1f, bf16_t* __restrict__ A0_0, bf16_t* __restrict__ A1_0)
{
    const int i = blockIdx.x * 256 + threadIdx.x;   // over 262144
    const int m = i >> 10, c = i & 1023;
    const float h0 = hidden[i], h1 = hidden[262144 + i];
    h0f[i] = h0; h1f[i] = h1;
    A0_0[(size_t)m * 1280 + 256 + c] = (bf16_t)h0;
    A1_0[(size_t)m * 2048 + 1024 + c] = (bf16_t)h1;
    if (c < 256) A0_0[(size_t)m * 1280 + c] = (bf16_t)0.f;
}

// ---------------------------------------------------------------------------
// LayerNorm + exact GELU, bf16 output. One row per 256-thread block.
// ---------------------------------------------------------------------------
__device__ __forceinline__ float block_reduce_sum(float v, float* red)
{
#pragma unroll
    for (int o = 32; o > 0; o >>= 1) v += __shfl_xor(v, o, 64);
    const int wid = threadIdx.x >> 6;
    if ((threadIdx.x & 63) == 0) red[wid] = v;
    __syncthreads();
    float s = red[0] + red[1] + red[2] + red[3];
    __syncthreads();
    return s;
}

template <int N>
__global__ __launch_bounds__(256) void ln_gelu(
    const float* __restrict__ X, const float* __restrict__ g,
    const float* __restrict__ b, bf16_t* __restrict__ Y)
{
    __shared__ float red[4];
    const int row = blockIdx.x;
    const int tid = threadIdx.x;
    constexpr int PT = N / 256;
    float v[PT];
    float s = 0.f;
#pragma unroll
    for (int i = 0; i < PT; i++) {
        v[i] = X[(size_t)row * N + tid + i * 256];
        s += v[i];
    }
    const float mu = block_reduce_sum(s, red) * (1.f / N);
    float s2 = 0.f;
#pragma unroll
    for (int i = 0; i < PT; i++) { float d = v[i] - mu; s2 += d * d; }
    const float var = block_reduce_sum(s2, red) * (1.f / N);
    const float inv = rsqrtf(var + 1e-5f);
#pragma unroll
    for (int i = 0; i < PT; i++) {
        const int c = tid + i * 256;
        const float t = (v[i] - mu) * inv * g[c] + b[c];
        Y[(size_t)row * N + c] = (bf16_t)(0.5f * t * (1.f + erff(t * 0.70710678118654752f)));
    }
}

// ---------------------------------------------------------------------------
// softmax over logits rows; writes dout[b,t,:] fp32 and feedback bf16 into A0
// ---------------------------------------------------------------------------
__global__ __launch_bounds__(256) void softmax_fb(
    const float* __restrict__ logits, float* __restrict__ dout,
    bf16_t* __restrict__ a0w, int t)
{
    const int wv = threadIdx.x >> 6, lane = threadIdx.x & 63;
    const int row = blockIdx.x * 4 + wv;
    float v[4];
#pragma unroll
    for (int j = 0; j < 4; j++) v[j] = logits[(size_t)row * 256 + lane + 64 * j];
    float mx = fmaxf(fmaxf(v[0], v[1]), fmaxf(v[2], v[3]));
#pragma unroll
    for (int o = 32; o > 0; o >>= 1) mx = fmaxf(mx, __shfl_xor(mx, o, 64));
    float e[4], s = 0.f;
#pragma unroll
    for (int j = 0; j < 4; j++) { e[j] = expf(v[j] - mx); s += e[j]; }
#pragma unroll
    for (int o = 32; o > 0; o >>= 1) s += __shfl_xor(s, o, 64);
    const float inv = 1.f / s;
#pragma unroll
    for (int j = 0; j < 4; j++) {
        const float p = e[j] * inv;
        const int c = lane + 64 * j;
        dout[((size_t)row * 64 + t) * 256 + c] = p;
        a0w[(size_t)row * 1280 + c] = (bf16_t)p;
    }
}

extern "C" void kernel_launch(void* const* d_in, const int* in_sizes, int n_in,
                              void* d_out, int out_size, void* d_ws, size_t ws_size,
                              hipStream_t stream)
{
    const float* hidden = (const float*)d_in[0];
    const float* W_ih0  = (const float*)d_in[1];
    const float* W_hh0  = (const float*)d_in[2];
    const float* b_ih0  = (const float*)d_in[3];
    const float* b_hh0  = (const float*)d_in[4];
    const float* W_ih1  = (const float*)d_in[5];
    const float* W_hh1  = (const float*)d_in[6];
    const float* b_ih1  = (const float*)d_in[7];
    const float* b_hh1  = (const float*)d_in[8];
    const float* fc1_w  = (const float*)d_in[9];
    const float* fc1_b  = (const float*)d_in[10];
    const float* ln1_g  = (const float*)d_in[11];
    const float* ln1_b  = (const float*)d_in[12];
    const float* fc2_w  = (const float*)d_in[13];
    const float* fc2_b  = (const float*)d_in[14];
    const float* ln2_g  = (const float*)d_in[15];
    const float* ln2_b  = (const float*)d_in[16];
    const float* fc3_w  = (const float*)d_in[17];
    const float* fc3_b  = (const float*)d_in[18];
    float* dout = (float*)d_out;

    char* p = (char*)d_ws;
    auto alloc = [&](size_t bytes) { void* r = (void*)p; p += (bytes + 255) & ~(size_t)255; return r; };
    float*  h0f   = (float*)alloc(262144 * 4);
    float*  h1f   = (float*)alloc(262144 * 4);
    bf16_t* A0[2] = { (bf16_t*)alloc(256 * 1280 * 2), (bf16_t*)alloc(256 * 1280 * 2) };
    bf16_t* A1[2] = { (bf16_t*)alloc(256 * 2048 * 2), (bf16_t*)alloc(256 * 2048 * 2) };
    bf16_t* h1b   = (bf16_t*)alloc(262144 * 2);
    float*  a1r   = (float*)alloc(262144 * 4);
    bf16_t* a1b   = (bf16_t*)alloc(262144 * 2);
    float*  a2r   = (float*)alloc(131072 * 4);
    bf16_t* a2b   = (bf16_t*)alloc(131072 * 2);
    float*  logits= (float*)alloc(65536 * 4);
    float*  b4_0  = (float*)alloc(4096 * 4);
    float*  b4_1  = (float*)alloc(4096 * 4);
    bf16_t* W4_0  = (bf16_t*)alloc((size_t)4096 * 1280 * 2);
    bf16_t* W4_1  = (bf16_t*)alloc((size_t)4096 * 2048 * 2);
    bf16_t* fc1wb = (bf16_t*)alloc((size_t)1048576 * 2);
    bf16_t* fc2wb = (bf16_t*)alloc((size_t)524288 * 2);
    bf16_t* fc3wb = (bf16_t*)alloc((size_t)131072 * 2);

    // weight prep (runs every launch; ~40us total, graph-safe)
    build_w4<<<5120, 256, 0, stream>>>(W_ih0, W_hh0, b_ih0, b_hh0, W4_0, b4_0, 256);
    build_w4<<<8192, 256, 0, stream>>>(W_ih1, W_hh1, b_ih1, b_hh1, W4_1, b4_1, 1024);
    conv_bf16<<<1024, 256, 0, stream>>>(fc1_w, fc1wb);
    conv_bf16<<<512, 256, 0, stream>>>(fc2_w, fc2wb);
    conv_bf16<<<128, 256, 0, stream>>>(fc3_w, fc3wb);
    init_state<<<1024, 256, 0, stream>>>(hidden, h0f, h1f, A0[0], A1[0]);

    for (int t = 0; t < 64; t++) {
        bf16_t* A0r = A0[t & 1];
        bf16_t* A0w = A0[(t + 1) & 1];
        bf16_t* A1r = A1[t & 1];
        bf16_t* A1w = A1[(t + 1) & 1];

        // GRU layer 0 (fused GEMM + combine): reads A0r=[out|h0], updates h0f,
        // writes bf16 h0 into A1r[:, :1024] (gru1 reads this step) and
        // A0w[:, 256:1280] (gru0 reads next step).
        gemm_mfma<4, 1><<<dim3(64, 4), 256, 0, stream>>>(
            A0r, W4_0, b4_0, 1280, nullptr, 0,
            h0f, A1r, 2048, 0, A0w, 1280, 256);
        // GRU layer 1: reads A1r=[h0_new|h1_old], updates h1f, writes bf16 h1
        // into A1w[:, 1024:] (next step) and h1b (fc1 input).
        gemm_mfma<4, 1><<<dim3(64, 4), 256, 0, stream>>>(
            A1r, W4_1, b4_1, 2048, nullptr, 0,
            h1f, A1w, 2048, 1024, h1b, 1024, 0);
        // FC head
        gemm_mfma<2, 0><<<dim3(16, 8), 128, 0, stream>>>(
            h1b, fc1wb, fc1_b, 1024, a1r, 1024, nullptr, nullptr, 0, 0, nullptr, 0, 0);
        ln_gelu<1024><<<256, 256, 0, stream>>>(a1r, ln1_g, ln1_b, a1b);
        gemm_mfma<2, 0><<<dim3(8, 8), 128, 0, stream>>>(
            a1b, fc2wb, fc2_b, 1024, a2r, 512, nullptr, nullptr, 0, 0, nullptr, 0, 0);
        ln_gelu<512><<<256, 256, 0, stream>>>(a2r, ln2_g, ln2_b, a2b);
        gemm_mfma<2, 0><<<dim3(4, 8), 128, 0, stream>>>(
            a2b, fc3wb, fc3_b, 512, logits, 256, nullptr, nullptr, 0, 0, nullptr, 0, 0);
        softmax_fb<<<64, 256, 0, stream>>>(logits, dout, A0w, t);
    }
}